// Round 3
// baseline (4648.926 us; speedup 1.0000x reference)
//
#include <hip/hip_runtime.h>
#include <math.h>

typedef float  v4f __attribute__((ext_vector_type(4)));
typedef double v2d __attribute__((ext_vector_type(2)));

#define NB   16384
#define KCTX 1284
#define CSL  (KCTX/4)    // 321 float4 per ctx row

// ---------------- ctx concat [state | task | action], unpadded K=1284 -------
__global__ __launch_bounds__(256) void k_build_ctx(
    const float* __restrict__ state, const float* __restrict__ task,
    const float* __restrict__ action, float* __restrict__ Cg)
{
  int idx = blockIdx.x * 256 + threadIdx.x;      // float4 slot
  if (idx >= NB * CSL) return;
  int b = idx / CSL, s = idx - b * CSL;
  v4f v;
  if (s < 256)       v = *((const v4f*)state  + (size_t)b * 256 + s);
  else if (s == 256) v = *((const v4f*)task   + b);
  else               v = *((const v4f*)action + (size_t)b * 64 + (s - 257));
  *((v4f*)Cg + idx) = v;
}

__device__ __forceinline__ unsigned long long f64_ord(double f) {
  unsigned long long u = (unsigned long long)__double_as_longlong(f);
  return (u & 0x8000000000000000ull) ? ~u : (u | 0x8000000000000000ull);
}

// ---------------- fp64-accumulate GEMM: C[M,N] = A[M,K] * W[N,K]^T + bias ----
// EPI: 0 = store f64, 2 = row-argmax only (packed atomicMax, no C store),
//      3 = store f32, 4 = tanh -> store f32
// ASRC: 0 = A is fp32 (K may be non-multiple of 16), 1 = A is fp64 (K%16==0)
#define TM 128
#define TN 128
#define TK 16
#define LROW 160   // f64 per kk-row: 16 groups * (8 data + 2 pad) -> bank-spread

template<int EPI, int ASRC>
__global__ __launch_bounds__(256, 2) void g64(
    const void* __restrict__ Av, const float* __restrict__ W,
    const float* __restrict__ bias, void* __restrict__ Cv,
    unsigned long long* __restrict__ kpk, int N, int K)
{
  __shared__ __align__(16) double As[TK * LROW];
  __shared__ __align__(16) double Bs[TK * LROW];

  const int tid = threadIdx.x;
  const int tx = tid & 15, ty = tid >> 4;
  const int row0 = blockIdx.x * TM;
  const int col0 = blockIdx.y * TN;
  const int lr = tid >> 1;          // tile row/col 0..127 for the loader
  const int lc = (tid & 1) * 8;     // k offset 0 or 8
  const int wbase = (lr >> 3) * 10 + (lr & 7);

  double acc[8][8];
  #pragma unroll
  for (int i = 0; i < 8; ++i)
    #pragma unroll
    for (int j = 0; j < 8; ++j) acc[i][j] = 0.0;

  for (int k0 = 0; k0 < K; k0 += TK) {
    double ad[8], wd[8];
    const int kb = k0 + lc;
    if (ASRC == 0) {
      const float* Ap = (const float*)Av + (size_t)(row0 + lr) * K;
      if (kb + 8 <= K) {
        v4f x0 = *(const v4f*)(Ap + kb), x1 = *(const v4f*)(Ap + kb + 4);
        ad[0] = x0.x; ad[1] = x0.y; ad[2] = x0.z; ad[3] = x0.w;
        ad[4] = x1.x; ad[5] = x1.y; ad[6] = x1.z; ad[7] = x1.w;
      } else {
        #pragma unroll
        for (int j = 0; j < 8; ++j) ad[j] = (kb + j < K) ? (double)Ap[kb + j] : 0.0;
      }
    } else {
      const double* Ap = (const double*)Av + (size_t)(row0 + lr) * K + kb;
      v2d d0 = *(const v2d*)Ap,       d1 = *(const v2d*)(Ap + 2);
      v2d d2 = *(const v2d*)(Ap + 4), d3 = *(const v2d*)(Ap + 6);
      ad[0] = d0.x; ad[1] = d0.y; ad[2] = d1.x; ad[3] = d1.y;
      ad[4] = d2.x; ad[5] = d2.y; ad[6] = d3.x; ad[7] = d3.y;
    }
    {
      const float* Wp = W + (size_t)(col0 + lr) * K;
      if (kb + 8 <= K) {
        v4f w0 = *(const v4f*)(Wp + kb), w1 = *(const v4f*)(Wp + kb + 4);
        wd[0] = w0.x; wd[1] = w0.y; wd[2] = w0.z; wd[3] = w0.w;
        wd[4] = w1.x; wd[5] = w1.y; wd[6] = w1.z; wd[7] = w1.w;
      } else {
        #pragma unroll
        for (int j = 0; j < 8; ++j) wd[j] = (kb + j < K) ? (double)Wp[kb + j] : 0.0;
      }
    }
    __syncthreads();
    #pragma unroll
    for (int j = 0; j < 8; ++j) {
      As[(lc + j) * LROW + wbase] = ad[j];
      Bs[(lc + j) * LROW + wbase] = wd[j];
    }
    __syncthreads();
    #pragma unroll
    for (int kk = 0; kk < TK; ++kk) {
      double a[8], b[8];
      const v2d* ap = (const v2d*)(As + kk * LROW + ty * 10);
      const v2d* bp = (const v2d*)(Bs + kk * LROW + tx * 10);
      *(v2d*)&a[0] = ap[0]; *(v2d*)&a[2] = ap[1];
      *(v2d*)&a[4] = ap[2]; *(v2d*)&a[6] = ap[3];
      *(v2d*)&b[0] = bp[0]; *(v2d*)&b[2] = bp[1];
      *(v2d*)&b[4] = bp[2]; *(v2d*)&b[6] = bp[3];
      #pragma unroll
      for (int i = 0; i < 8; ++i)
        #pragma unroll
        for (int j = 0; j < 8; ++j)
          acc[i][j] = fma(a[i], b[j], acc[i][j]);
    }
  }

  double bb[8];
  #pragma unroll
  for (int j = 0; j < 8; ++j) bb[j] = (double)bias[col0 + tx * 8 + j];

  if (EPI == 0) {
    #pragma unroll
    for (int i = 0; i < 8; ++i) {
      int r = row0 + ty * 8 + i;
      double* Cp = (double*)Cv + (size_t)r * N + col0 + tx * 8;
      #pragma unroll
      for (int p = 0; p < 4; ++p) {
        v2d o;
        o.x = acc[i][2 * p]     + bb[2 * p];
        o.y = acc[i][2 * p + 1] + bb[2 * p + 1];
        *(v2d*)(Cp + 2 * p) = o;
      }
    }
  } else if (EPI == 3 || EPI == 4) {
    #pragma unroll
    for (int i = 0; i < 8; ++i) {
      int r = row0 + ty * 8 + i;
      float* Cp = (float*)Cv + (size_t)r * N + col0 + tx * 8;
      v4f o0, o1;
      if (EPI == 4) {
        o0.x = (float)tanh(acc[i][0] + bb[0]); o0.y = (float)tanh(acc[i][1] + bb[1]);
        o0.z = (float)tanh(acc[i][2] + bb[2]); o0.w = (float)tanh(acc[i][3] + bb[3]);
        o1.x = (float)tanh(acc[i][4] + bb[4]); o1.y = (float)tanh(acc[i][5] + bb[5]);
        o1.z = (float)tanh(acc[i][6] + bb[6]); o1.w = (float)tanh(acc[i][7] + bb[7]);
      } else {
        o0.x = (float)(acc[i][0] + bb[0]); o0.y = (float)(acc[i][1] + bb[1]);
        o0.z = (float)(acc[i][2] + bb[2]); o0.w = (float)(acc[i][3] + bb[3]);
        o1.x = (float)(acc[i][4] + bb[4]); o1.y = (float)(acc[i][5] + bb[5]);
        o1.z = (float)(acc[i][6] + bb[6]); o1.w = (float)(acc[i][7] + bb[7]);
      }
      *(v4f*)Cp = o0; *(v4f*)(Cp + 4) = o1;
    }
  } else {  // EPI == 2: row argmax, packed (48-bit value | 16-bit ~col) atomicMax
    #pragma unroll
    for (int i = 0; i < 8; ++i) {
      double best = acc[i][0] + bb[0];
      int bcol = col0 + tx * 8;
      #pragma unroll
      for (int j = 1; j < 8; ++j) {
        double v = acc[i][j] + bb[j];
        if (v > best) { best = v; bcol = col0 + tx * 8 + j; }
      }
      #pragma unroll
      for (int d = 1; d < 16; d <<= 1) {
        double ov = __shfl_xor(best, d);
        int    oc = __shfl_xor(bcol, d);
        if (ov > best || (ov == best && oc < bcol)) { best = ov; bcol = oc; }
      }
      if (tx == 0) {
        unsigned long long key =
            (f64_ord(best) & ~0xFFFFull) | ((~(unsigned)bcol) & 0xFFFFu);
        atomicMax(&kpk[row0 + ty * 8 + i], key);
      }
    }
  }
}

// ---------------- kwta on fp64: exact radix-select of k-th largest ----------
__global__ __launch_bounds__(256) void k_kwta64(
    double* __restrict__ X, int N, const unsigned long long* __restrict__ kpk)
{
  const int row = blockIdx.x;
  const int tid = threadIdx.x;
  double* x = X + (size_t)row * N;
  __shared__ unsigned long long su[1024];
  __shared__ int hist[256];
  __shared__ int scan[256];
  __shared__ int s_bin, s_base, s_cnt;

  unsigned long long p = kpk[row];
  int k = (int)((~p) & 0xFFFFull);

  for (int j = tid; j < N; j += 256) su[j] = f64_ord(x[j]);
  __syncthreads();

  unsigned long long uth = 0xFFFFFFFFFFFFFFFFull;   // k==0: damp everything
  if (k > 0) {
    int t = N - k;                 // ascending 0-indexed rank of k-th largest
    unsigned long long prefix = 0;
    for (int shift = 56; shift >= 0; shift -= 8) {
      hist[tid] = 0;
      __syncthreads();
      unsigned long long pm =
          (shift == 56) ? 0ull : ~((1ull << (shift + 8)) - 1ull);
      for (int j = tid; j < N; j += 256) {
        unsigned long long u = su[j];
        if ((u & pm) == prefix) atomicAdd(&hist[(int)((u >> shift) & 255)], 1);
      }
      __syncthreads();
      int v = hist[tid];
      scan[tid] = v;
      __syncthreads();
      for (int d = 1; d < 256; d <<= 1) {
        int add = (tid >= d) ? scan[tid - d] : 0;
        __syncthreads();
        scan[tid] += add;
        __syncthreads();
      }
      int incl = scan[tid];
      int excl = incl - hist[tid];
      if (hist[tid] > 0 && t >= excl && t < incl) {
        s_bin = tid; s_base = excl; s_cnt = hist[tid];
      }
      __syncthreads();
      prefix |= ((unsigned long long)s_bin) << shift;
      t -= s_base;
      int cnt = s_cnt;
      __syncthreads();
      if (cnt == 1) break;   // unique element under this prefix: zero-filled
                             // low bits still classify every element correctly
    }
    uth = prefix;
  }
  __syncthreads();
  for (int j = tid; j < N; j += 256) {
    if (su[j] < uth) x[j] = x[j] / 3.0;
  }
}

// ---------------- launch ----------------
extern "C" void kernel_launch(void* const* d_in, const int* in_sizes, int n_in,
                              void* d_out, int out_size, void* d_ws, size_t ws_size,
                              hipStream_t stream)
{
  const float* state   = (const float*)d_in[0];
  const float* task    = (const float*)d_in[1];
  const float* action  = (const float*)d_in[2];
  const float* W_cx1_1 = (const float*)d_in[3];  const float* b_cx1_1 = (const float*)d_in[4];
  const float* W_cx1_2 = (const float*)d_in[5];  const float* b_cx1_2 = (const float*)d_in[6];
  const float* W_cx2_1 = (const float*)d_in[7];  const float* b_cx2_1 = (const float*)d_in[8];
  const float* W_cx2_2 = (const float*)d_in[9];  const float* b_cx2_2 = (const float*)d_in[10];
  const float* W_cx3_1 = (const float*)d_in[11]; const float* b_cx3_1 = (const float*)d_in[12];
  const float* W_cx3_2 = (const float*)d_in[13]; const float* b_cx3_2 = (const float*)d_in[14];
  const float* W_l1    = (const float*)d_in[15]; const float* b_l1    = (const float*)d_in[16];
  const float* W_l2    = (const float*)d_in[17]; const float* b_l2    = (const float*)d_in[18];
  const float* W_l3    = (const float*)d_in[19]; const float* b_l3    = (const float*)d_in[20];
  const float* W_l4    = (const float*)d_in[21]; const float* b_l4    = (const float*)d_in[22];

  // ---- workspace overlay (peak 218.37 MB, <= round-1's proven footprint) ----
  // region A [0, 134.22 MB):  tower h (fp32) -> a1 (fp64) -> a3 (fp64)
  // region B [134.22, 218.37): Cg (fp32)     -> a2 (fp64)
  // kpk (0.39 MB) lives at the front of d_out (16.8 MB) and is fully consumed
  // before the final GEMM overwrites d_out.
  char* wsb = (char*)d_ws;
  double* A1 = (double*)wsb;                       // 16384*1024*8 = 134,217,728
  float*  Hf = (float*)wsb;                        // towers' h, <= 67.1 MB
  double* A3 = (double*)wsb;                       // 16384*256*8 = 33.6 MB
  float*  Cg = (float*)(wsb + 134217728ULL);       // 16384*1284*4 = 84,148,224
  double* A2 = (double*)(wsb + 134217728ULL);      // 16384*512*8 = 67.1 MB
  unsigned long long* kpk = (unsigned long long*)d_out;

  dim3 blk(256);

  k_build_ctx<<<(NB * CSL) / 256, blk, 0, stream>>>(state, task, action, Cg);
  (void)hipMemsetAsync(kpk, 0, (size_t)3 * NB * 8, stream);

  // gate towers: h = tanh(ctx @ Wa^T + ba) (fp64 math, fp32 store);
  // then logits + fused row-argmax (softmax elided: argmax-invariant)
  g64<4,0><<<dim3(NB/TM, 1024/TN), blk, 0, stream>>>(Cg, W_cx1_1, b_cx1_1, Hf, nullptr, 1024, KCTX);
  g64<2,0><<<dim3(NB/TM, 1024/TN), blk, 0, stream>>>(Hf, W_cx1_2, b_cx1_2, nullptr, kpk,        1024, 1024);
  g64<4,0><<<dim3(NB/TM,  512/TN), blk, 0, stream>>>(Cg, W_cx2_1, b_cx2_1, Hf, nullptr, 512, KCTX);
  g64<2,0><<<dim3(NB/TM,  512/TN), blk, 0, stream>>>(Hf, W_cx2_2, b_cx2_2, nullptr, kpk + NB,    512,  512);
  g64<4,0><<<dim3(NB/TM,  256/TN), blk, 0, stream>>>(Cg, W_cx3_1, b_cx3_1, Hf, nullptr, 256, KCTX);
  g64<2,0><<<dim3(NB/TM,  256/TN), blk, 0, stream>>>(Hf, W_cx3_2, b_cx3_2, nullptr, kpk + 2*NB,  256,  256);

  // main chain, fp64 end to end
  g64<0,0><<<dim3(NB/TM, 1024/TN), blk, 0, stream>>>(Cg, W_l1, b_l1, A1, nullptr, 1024, KCTX);
  k_kwta64<<<NB, blk, 0, stream>>>(A1, 1024, kpk);
  g64<0,1><<<dim3(NB/TM,  512/TN), blk, 0, stream>>>(A1, W_l2, b_l2, A2, nullptr,  512, 1024);
  k_kwta64<<<NB, blk, 0, stream>>>(A2,  512, kpk + NB);
  g64<0,1><<<dim3(NB/TM,  256/TN), blk, 0, stream>>>(A2, W_l3, b_l3, A3, nullptr,  256,  512);
  k_kwta64<<<NB, blk, 0, stream>>>(A3,  256, kpk + 2*NB);
  g64<3,1><<<dim3(NB/TM,  256/TN), blk, 0, stream>>>(A3, W_l4, b_l4, d_out, nullptr, 256, 256);
}

// Round 5
// 3907.188 us; speedup vs baseline: 1.1898x; 1.1898x over previous
//
#include <hip/hip_runtime.h>
#include <math.h>

typedef float  v4f __attribute__((ext_vector_type(4)));
typedef double v2d __attribute__((ext_vector_type(2)));
typedef double v4d __attribute__((ext_vector_type(4)));

#define NB   16384
#define KCTX 1284
#define CSL  (KCTX/4)    // 321 float4 per ctx row

// ---- fp64 MFMA: D[16x16] += A[16x4] * B[4x16], per-wave ----
#if defined(__has_builtin)
#  if __has_builtin(__builtin_amdgcn_mfma_f64_16x16x4f64)
#    define MFMA64(a, b, c) __builtin_amdgcn_mfma_f64_16x16x4f64((a), (b), (c), 0, 0, 0)
#  endif
#endif
#ifndef MFMA64
static __device__ __forceinline__ v4d mfma64_asm(double a, double b, v4d c) {
  asm volatile("v_mfma_f64_16x16x4_f64 %0, %1, %2, %0" : "+v"(c) : "v"(a), "v"(b));
  return c;
}
#  define MFMA64(a, b, c) mfma64_asm((a), (b), (c))
#endif

// ---------------- ctx concat [state | task | action], unpadded K=1284 -------
__global__ __launch_bounds__(256) void k_build_ctx(
    const float* __restrict__ state, const float* __restrict__ task,
    const float* __restrict__ action, float* __restrict__ Cg)
{
  int idx = blockIdx.x * 256 + threadIdx.x;      // float4 slot
  if (idx >= NB * CSL) return;
  int b = idx / CSL, s = idx - b * CSL;
  v4f v;
  if (s < 256)       v = *((const v4f*)state  + (size_t)b * 256 + s);
  else if (s == 256) v = *((const v4f*)task   + b);
  else               v = *((const v4f*)action + (size_t)b * 64 + (s - 257));
  *((v4f*)Cg + idx) = v;
}

__device__ __forceinline__ unsigned long long f64_ord(double f) {
  unsigned long long u = (unsigned long long)__double_as_longlong(f);
  return (u & 0x8000000000000000ull) ? ~u : (u | 0x8000000000000000ull);
}

// ---------------- fp64-MFMA GEMM: C[M,N] = A[M,K] * W[N,K]^T + bias ---------
// EPI: 0 = store f64, 2 = row-argmax only (packed atomicMax, no C store),
//      3 = store f32, 4 = tanh -> store f32
// ASRC: 0 = A is fp32 (K may be non-multiple of 16), 1 = A is fp64 (K%16==0)
// D-layout (f64 16x16x4, empirically pinned in r4 post-mortem):
//   col = lane&15, row = 4*reg + (lane>>4)     <-- reg-major rows
#define TM 128
#define TN 128
#define TK 16
#define LROW 130   // 128 + 2 f64 pad: rotates k-row bank phase

template<int EPI, int ASRC>
__global__ __launch_bounds__(256, 2) void g64m(
    const void* __restrict__ Av, const float* __restrict__ W,
    const float* __restrict__ bias, void* __restrict__ Cv,
    unsigned long long* __restrict__ kpk, int N, int K)
{
  __shared__ __align__(16) double As[TK * LROW];   // k-major: As[k][m]
  __shared__ __align__(16) double Ws[TK * LROW];   // k-major: Ws[k][n]

  const int tid  = threadIdx.x;
  const int lane = tid & 63;
  const int wid  = tid >> 6;       // wave 0..3
  const int wm   = wid >> 1;       // wave-tile row 0..1 (64 rows each)
  const int wn   = wid & 1;        // wave-tile col 0..1 (64 cols each)
  const int grp  = lane >> 4;      // k-slot within a K4 step / row sub-index
  const int lid  = lane & 15;      // m/n index within a 16-wide fragment
  const int row0 = blockIdx.x * TM;
  const int col0 = blockIdx.y * TN;

  const int lr = tid >> 1;          // tile row/col 0..127 for the loader
  const int lc = (tid & 1) * 8;     // k offset 0 or 8

  v4d acc[4][4];
  #pragma unroll
  for (int i = 0; i < 4; ++i)
    #pragma unroll
    for (int j = 0; j < 4; ++j) { acc[i][j][0] = 0.0; acc[i][j][1] = 0.0;
                                  acc[i][j][2] = 0.0; acc[i][j][3] = 0.0; }

  for (int k0 = 0; k0 < K; k0 += TK) {
    double ad[8], wd[8];
    const int kb = k0 + lc;
    if (ASRC == 0) {
      const float* Ap = (const float*)Av + (size_t)(row0 + lr) * K;
      if (kb + 8 <= K) {
        v4f x0 = *(const v4f*)(Ap + kb), x1 = *(const v4f*)(Ap + kb + 4);
        ad[0] = x0.x; ad[1] = x0.y; ad[2] = x0.z; ad[3] = x0.w;
        ad[4] = x1.x; ad[5] = x1.y; ad[6] = x1.z; ad[7] = x1.w;
      } else {
        #pragma unroll
        for (int j = 0; j < 8; ++j) ad[j] = (kb + j < K) ? (double)Ap[kb + j] : 0.0;
      }
    } else {
      const double* Ap = (const double*)Av + (size_t)(row0 + lr) * K + kb;
      v2d d0 = *(const v2d*)Ap,       d1 = *(const v2d*)(Ap + 2);
      v2d d2 = *(const v2d*)(Ap + 4), d3 = *(const v2d*)(Ap + 6);
      ad[0] = d0.x; ad[1] = d0.y; ad[2] = d1.x; ad[3] = d1.y;
      ad[4] = d2.x; ad[5] = d2.y; ad[6] = d3.x; ad[7] = d3.y;
    }
    {
      const float* Wp = W + (size_t)(col0 + lr) * K;
      if (kb + 8 <= K) {
        v4f w0 = *(const v4f*)(Wp + kb), w1 = *(const v4f*)(Wp + kb + 4);
        wd[0] = w0.x; wd[1] = w0.y; wd[2] = w0.z; wd[3] = w0.w;
        wd[4] = w1.x; wd[5] = w1.y; wd[6] = w1.z; wd[7] = w1.w;
      } else {
        #pragma unroll
        for (int j = 0; j < 8; ++j) wd[j] = (kb + j < K) ? (double)Wp[kb + j] : 0.0;
      }
    }
    __syncthreads();   // previous iteration's fragment reads complete
    #pragma unroll
    for (int j = 0; j < 8; ++j) {
      As[(lc + j) * LROW + lr] = ad[j];
      Ws[(lc + j) * LROW + lr] = wd[j];
    }
    __syncthreads();
    #pragma unroll
    for (int ks = 0; ks < 4; ++ks) {
      const double* Ar = As + (ks * 4 + grp) * LROW + wm * 64 + lid;
      const double* Br = Ws + (ks * 4 + grp) * LROW + wn * 64 + lid;
      double a[4], b[4];
      #pragma unroll
      for (int i = 0; i < 4; ++i) a[i] = Ar[i * 16];
      #pragma unroll
      for (int j = 0; j < 4; ++j) b[j] = Br[j * 16];
      #pragma unroll
      for (int i = 0; i < 4; ++i)
        #pragma unroll
        for (int j = 0; j < 4; ++j)
          acc[i][j] = MFMA64(a[i], b[j], acc[i][j]);
    }
  }

  double bb[4];
  #pragma unroll
  for (int j = 0; j < 4; ++j) bb[j] = (double)bias[col0 + wn * 64 + j * 16 + lid];

  // C/D layout: col = lane&15, row = 4*reg + (lane>>4)
  if (EPI == 0) {
    #pragma unroll
    for (int i = 0; i < 4; ++i)
      #pragma unroll
      for (int r = 0; r < 4; ++r) {
        int row = row0 + wm * 64 + i * 16 + r * 4 + grp;
        double* Cp = (double*)Cv + (size_t)row * N + col0 + wn * 64 + lid;
        #pragma unroll
        for (int j = 0; j < 4; ++j) Cp[j * 16] = acc[i][j][r] + bb[j];
      }
  } else if (EPI == 3 || EPI == 4) {
    #pragma unroll
    for (int i = 0; i < 4; ++i)
      #pragma unroll
      for (int r = 0; r < 4; ++r) {
        int row = row0 + wm * 64 + i * 16 + r * 4 + grp;
        float* Cp = (float*)Cv + (size_t)row * N + col0 + wn * 64 + lid;
        #pragma unroll
        for (int j = 0; j < 4; ++j) {
          double o = acc[i][j][r] + bb[j];
          if (EPI == 4) o = tanh(o);
          Cp[j * 16] = (float)o;
        }
      }
  } else {  // EPI == 2: row argmax, packed (48-bit value | 16-bit ~col) atomicMax
    #pragma unroll
    for (int i = 0; i < 4; ++i)
      #pragma unroll
      for (int r = 0; r < 4; ++r) {
        int row = row0 + wm * 64 + i * 16 + r * 4 + grp;
        double best = acc[i][0][r] + bb[0];
        int bcol = col0 + wn * 64 + lid;
        #pragma unroll
        for (int j = 1; j < 4; ++j) {
          double v = acc[i][j][r] + bb[j];
          if (v > best) { best = v; bcol = col0 + wn * 64 + j * 16 + lid; }
        }
        #pragma unroll
        for (int d = 1; d < 16; d <<= 1) {
          double ov = __shfl_xor(best, d);
          int    oc = __shfl_xor(bcol, d);
          if (ov > best || (ov == best && oc < bcol)) { best = ov; bcol = oc; }
        }
        if (lid == 0) {
          unsigned long long key =
              (f64_ord(best) & ~0xFFFFull) | ((~(unsigned)bcol) & 0xFFFFu);
          atomicMax(&kpk[row], key);
        }
      }
  }
}

// ---------------- kwta on fp64: exact radix-select of k-th largest ----------
__global__ __launch_bounds__(256) void k_kwta64(
    double* __restrict__ X, int N, const unsigned long long* __restrict__ kpk)
{
  const int row = blockIdx.x;
  const int tid = threadIdx.x;
  double* x = X + (size_t)row * N;
  __shared__ unsigned long long su[1024];
  __shared__ int hist[256];
  __shared__ int scan[256];
  __shared__ int s_bin, s_base, s_cnt;

  unsigned long long p = kpk[row];
  int k = (int)((~p) & 0xFFFFull);

  for (int j = tid; j < N; j += 256) su[j] = f64_ord(x[j]);
  __syncthreads();

  unsigned long long uth = 0xFFFFFFFFFFFFFFFFull;   // k==0: damp everything
  if (k > 0) {
    int t = N - k;                 // ascending 0-indexed rank of k-th largest
    unsigned long long prefix = 0;
    for (int shift = 56; shift >= 0; shift -= 8) {
      hist[tid] = 0;
      __syncthreads();
      unsigned long long pm =
          (shift == 56) ? 0ull : ~((1ull << (shift + 8)) - 1ull);
      for (int j = tid; j < N; j += 256) {
        unsigned long long u = su[j];
        if ((u & pm) == prefix) atomicAdd(&hist[(int)((u >> shift) & 255)], 1);
      }
      __syncthreads();
      int v = hist[tid];
      scan[tid] = v;
      __syncthreads();
      for (int d = 1; d < 256; d <<= 1) {
        int add = (tid >= d) ? scan[tid - d] : 0;
        __syncthreads();
        scan[tid] += add;
        __syncthreads();
      }
      int incl = scan[tid];
      int excl = incl - hist[tid];
      if (hist[tid] > 0 && t >= excl && t < incl) {
        s_bin = tid; s_base = excl; s_cnt = hist[tid];
      }
      __syncthreads();
      prefix |= ((unsigned long long)s_bin) << shift;
      t -= s_base;
      int cnt = s_cnt;
      __syncthreads();
      if (cnt == 1) break;   // unique element under this prefix: zero-filled
                             // low bits still classify every element correctly
    }
    uth = prefix;
  }
  __syncthreads();
  for (int j = tid; j < N; j += 256) {
    if (su[j] < uth) x[j] = x[j] / 3.0;
  }
}

// ---------------- launch ----------------
extern "C" void kernel_launch(void* const* d_in, const int* in_sizes, int n_in,
                              void* d_out, int out_size, void* d_ws, size_t ws_size,
                              hipStream_t stream)
{
  const float* state   = (const float*)d_in[0];
  const float* task    = (const float*)d_in[1];
  const float* action  = (const float*)d_in[2];
  const float* W_cx1_1 = (const float*)d_in[3];  const float* b_cx1_1 = (const float*)d_in[4];
  const float* W_cx1_2 = (const float*)d_in[5];  const float* b_cx1_2 = (const float*)d_in[6];
  const float* W_cx2_1 = (const float*)d_in[7];  const float* b_cx2_1 = (const float*)d_in[8];
  const float* W_cx2_2 = (const float*)d_in[9];  const float* b_cx2_2 = (const float*)d_in[10];
  const float* W_cx3_1 = (const float*)d_in[11]; const float* b_cx3_1 = (const float*)d_in[12];
  const float* W_cx3_2 = (const float*)d_in[13]; const float* b_cx3_2 = (const float*)d_in[14];
  const float* W_l1    = (const float*)d_in[15]; const float* b_l1    = (const float*)d_in[16];
  const float* W_l2    = (const float*)d_in[17]; const float* b_l2    = (const float*)d_in[18];
  const float* W_l3    = (const float*)d_in[19]; const float* b_l3    = (const float*)d_in[20];
  const float* W_l4    = (const float*)d_in[21]; const float* b_l4    = (const float*)d_in[22];

  // ---- workspace overlay (peak 218.37 MB, proven footprint) ----
  // region A [0, 134.22 MB):  tower h (fp32) -> a1 (fp64) -> a3 (fp64)
  // region B [134.22, 218.37): Cg (fp32)     -> a2 (fp64)
  // kpk (0.39 MB) lives at the front of d_out and is fully consumed before
  // the final GEMM overwrites d_out.
  char* wsb = (char*)d_ws;
  double* A1 = (double*)wsb;                       // 16384*1024*8 = 134,217,728
  float*  Hf = (float*)wsb;                        // towers' h, <= 67.1 MB
  double* A3 = (double*)wsb;                       // 16384*256*8 = 33.6 MB
  float*  Cg = (float*)(wsb + 134217728ULL);       // 16384*1284*4 = 84,148,224
  double* A2 = (double*)(wsb + 134217728ULL);      // 16384*512*8 = 67.1 MB
  unsigned long long* kpk = (unsigned long long*)d_out;

  dim3 blk(256);

  k_build_ctx<<<(NB * CSL) / 256, blk, 0, stream>>>(state, task, action, Cg);
  (void)hipMemsetAsync(kpk, 0, (size_t)3 * NB * 8, stream);

  // gate towers: h = tanh(ctx @ Wa^T + ba) (fp64 math, fp32 store);
  // then logits + fused row-argmax (softmax elided: argmax-invariant)
  g64m<4,0><<<dim3(NB/TM, 1024/TN), blk, 0, stream>>>(Cg, W_cx1_1, b_cx1_1, Hf, nullptr, 1024, KCTX);
  g64m<2,0><<<dim3(NB/TM, 1024/TN), blk, 0, stream>>>(Hf, W_cx1_2, b_cx1_2, nullptr, kpk,        1024, 1024);
  g64m<4,0><<<dim3(NB/TM,  512/TN), blk, 0, stream>>>(Cg, W_cx2_1, b_cx2_1, Hf, nullptr, 512, KCTX);
  g64m<2,0><<<dim3(NB/TM,  512/TN), blk, 0, stream>>>(Hf, W_cx2_2, b_cx2_2, nullptr, kpk + NB,    512,  512);
  g64m<4,0><<<dim3(NB/TM,  256/TN), blk, 0, stream>>>(Cg, W_cx3_1, b_cx3_1, Hf, nullptr, 256, KCTX);
  g64m<2,0><<<dim3(NB/TM,  256/TN), blk, 0, stream>>>(Hf, W_cx3_2, b_cx3_2, nullptr, kpk + 2*NB,  256,  256);

  // main chain, fp64 end to end
  g64m<0,0><<<dim3(NB/TM, 1024/TN), blk, 0, stream>>>(Cg, W_l1, b_l1, A1, nullptr, 1024, KCTX);
  k_kwta64<<<NB, blk, 0, stream>>>(A1, 1024, kpk);
  g64m<0,1><<<dim3(NB/TM,  512/TN), blk, 0, stream>>>(A1, W_l2, b_l2, A2, nullptr,  512, 1024);
  k_kwta64<<<NB, blk, 0, stream>>>(A2,  512, kpk + NB);
  g64m<0,1><<<dim3(NB/TM,  256/TN), blk, 0, stream>>>(A2, W_l3, b_l3, A3, nullptr,  256,  512);
  k_kwta64<<<NB, blk, 0, stream>>>(A3,  256, kpk + 2*NB);
  g64m<3,1><<<dim3(NB/TM,  256/TN), blk, 0, stream>>>(A3, W_l4, b_l4, d_out, nullptr, 256, 256);
}

// Round 6
// 3323.939 us; speedup vs baseline: 1.3986x; 1.1755x over previous
//
#include <hip/hip_runtime.h>
#include <math.h>

typedef float  v4f __attribute__((ext_vector_type(4)));
typedef double v2d __attribute__((ext_vector_type(2)));
typedef double v4d __attribute__((ext_vector_type(4)));

#define NB   16384
#define KCTX 1284
#define CSL  (KCTX/4)    // 321 float4 per ctx row

// ---- fp64 MFMA: D[16x16] += A[16x4] * B[4x16], per-wave ----
#if defined(__has_builtin)
#  if __has_builtin(__builtin_amdgcn_mfma_f64_16x16x4f64)
#    define MFMA64(a, b, c) __builtin_amdgcn_mfma_f64_16x16x4f64((a), (b), (c), 0, 0, 0)
#  endif
#endif
#ifndef MFMA64
static __device__ __forceinline__ v4d mfma64_asm(double a, double b, v4d c) {
  asm volatile("v_mfma_f64_16x16x4_f64 %0, %1, %2, %0" : "+v"(c) : "v"(a), "v"(b));
  return c;
}
#  define MFMA64(a, b, c) mfma64_asm((a), (b), (c))
#endif

// ---------------- ctx concat [state | task | action], unpadded K=1284 -------
__global__ __launch_bounds__(256) void k_build_ctx(
    const float* __restrict__ state, const float* __restrict__ task,
    const float* __restrict__ action, float* __restrict__ Cg)
{
  int idx = blockIdx.x * 256 + threadIdx.x;      // float4 slot
  if (idx >= NB * CSL) return;
  int b = idx / CSL, s = idx - b * CSL;
  v4f v;
  if (s < 256)       v = *((const v4f*)state  + (size_t)b * 256 + s);
  else if (s == 256) v = *((const v4f*)task   + b);
  else               v = *((const v4f*)action + (size_t)b * 64 + (s - 257));
  *((v4f*)Cg + idx) = v;
}

__device__ __forceinline__ unsigned long long f64_ord(double f) {
  unsigned long long u = (unsigned long long)__double_as_longlong(f);
  return (u & 0x8000000000000000ull) ? ~u : (u | 0x8000000000000000ull);
}

// ---------------- fp64-MFMA GEMM: C[M,N] = A[M,K] * W[N,K]^T + bias ---------
// EPI: 0 = store f64, 2 = row-argmax only (packed atomicMax, no C store),
//      3 = store f32, 4 = tanh -> store f32
// ASRC: 0 = A is fp32 (K may be non-multiple of 16), 1 = A is fp64 (K%16==0)
// D-layout (f64 16x16x4, pinned in r4 post-mortem, verified r5):
//   col = lane&15, row = 4*reg + (lane>>4)
// Occupancy design: tile 128x64, 4 waves of 64x32 -> acc[4][2] = 64 AGPR,
// ~135 regs/wave -> 3 waves/SIMD (was 2 at acc[4][4]); staging pipelined
// (t+1 global loads issue after t's ds_writes, drain under compute).
#define TM 128
#define TN 64
#define TK 16
#define LRA 130   // 128 + 2 f64 pad
#define LRB 66    // 64 + 2 f64 pad

template<int EPI, int ASRC>
__global__ __launch_bounds__(256, 3) void g64m(
    const void* __restrict__ Av, const float* __restrict__ W,
    const float* __restrict__ bias, void* __restrict__ Cv,
    unsigned long long* __restrict__ kpk, int N, int K)
{
  __shared__ __align__(16) double As[TK * LRA];   // k-major: As[k][m]
  __shared__ __align__(16) double Ws[TK * LRB];   // k-major: Ws[k][n]

  const int tid  = threadIdx.x;
  const int lane = tid & 63;
  const int wid  = tid >> 6;       // wave 0..3
  const int wm   = wid >> 1;       // wave-tile row 0..1 (64 rows each)
  const int wn   = wid & 1;        // wave-tile col 0..1 (32 cols each)
  const int grp  = lane >> 4;      // k-slot within a K4 step / row sub-index
  const int lid  = lane & 15;      // m/n index within a 16-wide fragment
  const int row0 = blockIdx.x * TM;
  const int col0 = blockIdx.y * TN;

  const int lrA = tid >> 1;          // A loader: row 0..127
  const int lcA = (tid & 1) * 8;     // A loader: k offset 0 or 8
  const int lrW = tid >> 2;          // W loader: row 0..63
  const int lcW = (tid & 3) * 4;     // W loader: k offset 0,4,8,12

  const float*  ApF = (const float*)Av  + (size_t)(row0 + lrA) * K;
  const double* ApD = (const double*)Av + (size_t)(row0 + lrA) * K;
  const float*  WpF = W + (size_t)(col0 + lrW) * K;

  double sa[8], sw[4];

  v4d acc[4][2];
  #pragma unroll
  for (int i = 0; i < 4; ++i)
    #pragma unroll
    for (int j = 0; j < 2; ++j) { acc[i][j][0] = 0.0; acc[i][j][1] = 0.0;
                                  acc[i][j][2] = 0.0; acc[i][j][3] = 0.0; }

  const int nt = (K + TK - 1) / TK;

  // ---- staged loads (masked tails) ----
  auto loadA = [&](int k0) {
    const int kb = k0 + lcA;
    if (ASRC == 0) {
      if (kb + 8 <= K) {
        v4f x0 = *(const v4f*)(ApF + kb), x1 = *(const v4f*)(ApF + kb + 4);
        sa[0] = x0.x; sa[1] = x0.y; sa[2] = x0.z; sa[3] = x0.w;
        sa[4] = x1.x; sa[5] = x1.y; sa[6] = x1.z; sa[7] = x1.w;
      } else {
        #pragma unroll
        for (int j = 0; j < 8; ++j) sa[j] = (kb + j < K) ? (double)ApF[kb + j] : 0.0;
      }
    } else {
      const double* p = ApD + kb;
      v2d d0 = *(const v2d*)p,       d1 = *(const v2d*)(p + 2);
      v2d d2 = *(const v2d*)(p + 4), d3 = *(const v2d*)(p + 6);
      sa[0] = d0.x; sa[1] = d0.y; sa[2] = d1.x; sa[3] = d1.y;
      sa[4] = d2.x; sa[5] = d2.y; sa[6] = d3.x; sa[7] = d3.y;
    }
  };
  auto loadW = [&](int k0) {
    const int kb = k0 + lcW;
    if (kb + 4 <= K) {
      v4f w0 = *(const v4f*)(WpF + kb);
      sw[0] = w0.x; sw[1] = w0.y; sw[2] = w0.z; sw[3] = w0.w;
    } else {
      #pragma unroll
      for (int j = 0; j < 4; ++j) sw[j] = (kb + j < K) ? (double)WpF[kb + j] : 0.0;
    }
  };

  loadA(0); loadW(0);

  for (int t = 0; t < nt; ++t) {
    __syncthreads();   // readers of previous tile done; LDS reusable
    #pragma unroll
    for (int j = 0; j < 8; ++j) As[(lcA + j) * LRA + lrA] = sa[j];
    #pragma unroll
    for (int j = 0; j < 4; ++j) Ws[(lcW + j) * LRB + lrW] = sw[j];
    if (t + 1 < nt) { loadA((t + 1) * TK); loadW((t + 1) * TK); }  // in flight under compute
    __syncthreads();   // tile t visible
    #pragma unroll
    for (int ks = 0; ks < 4; ++ks) {
      const double* Ar = As + (ks * 4 + grp) * LRA + wm * 64 + lid;
      const double* Br = Ws + (ks * 4 + grp) * LRB + wn * 32 + lid;
      double a[4], b[2];
      #pragma unroll
      for (int i = 0; i < 4; ++i) a[i] = Ar[i * 16];
      #pragma unroll
      for (int j = 0; j < 2; ++j) b[j] = Br[j * 16];
      #pragma unroll
      for (int i = 0; i < 4; ++i)
        #pragma unroll
        for (int j = 0; j < 2; ++j)
          acc[i][j] = MFMA64(a[i], b[j], acc[i][j]);
    }
  }

  double bb[2];
  #pragma unroll
  for (int j = 0; j < 2; ++j) bb[j] = (double)bias[col0 + wn * 32 + j * 16 + lid];

  // C/D layout: col = lane&15, row = 4*reg + (lane>>4)
  if (EPI == 0) {
    #pragma unroll
    for (int i = 0; i < 4; ++i)
      #pragma unroll
      for (int r = 0; r < 4; ++r) {
        int row = row0 + wm * 64 + i * 16 + r * 4 + grp;
        double* Cp = (double*)Cv + (size_t)row * N + col0 + wn * 32 + lid;
        #pragma unroll
        for (int j = 0; j < 2; ++j) Cp[j * 16] = acc[i][j][r] + bb[j];
      }
  } else if (EPI == 3 || EPI == 4) {
    #pragma unroll
    for (int i = 0; i < 4; ++i)
      #pragma unroll
      for (int r = 0; r < 4; ++r) {
        int row = row0 + wm * 64 + i * 16 + r * 4 + grp;
        float* Cp = (float*)Cv + (size_t)row * N + col0 + wn * 32 + lid;
        #pragma unroll
        for (int j = 0; j < 2; ++j) {
          double o = acc[i][j][r] + bb[j];
          if (EPI == 4) o = tanh(o);
          Cp[j * 16] = (float)o;
        }
      }
  } else {  // EPI == 2: row argmax, packed (48-bit value | 16-bit ~col) atomicMax
    #pragma unroll
    for (int i = 0; i < 4; ++i)
      #pragma unroll
      for (int r = 0; r < 4; ++r) {
        int row = row0 + wm * 64 + i * 16 + r * 4 + grp;
        double best = acc[i][0][r] + bb[0];
        int bcol = col0 + wn * 32 + lid;
        {
          double v = acc[i][1][r] + bb[1];
          if (v > best) { best = v; bcol = col0 + wn * 32 + 16 + lid; }
        }
        #pragma unroll
        for (int d = 1; d < 16; d <<= 1) {
          double ov = __shfl_xor(best, d);
          int    oc = __shfl_xor(bcol, d);
          if (ov > best || (ov == best && oc < bcol)) { best = ov; bcol = oc; }
        }
        if (lid == 0) {
          unsigned long long key =
              (f64_ord(best) & ~0xFFFFull) | ((~(unsigned)bcol) & 0xFFFFu);
          atomicMax(&kpk[row], key);
        }
      }
  }
}

// ---------------- kwta on fp64: exact radix-select of k-th largest ----------
__global__ __launch_bounds__(256) void k_kwta64(
    double* __restrict__ X, int N, const unsigned long long* __restrict__ kpk)
{
  const int row = blockIdx.x;
  const int tid = threadIdx.x;
  double* x = X + (size_t)row * N;
  __shared__ unsigned long long su[1024];
  __shared__ int hist[256];
  __shared__ int scan[256];
  __shared__ int s_bin, s_base, s_cnt;

  unsigned long long p = kpk[row];
  int k = (int)((~p) & 0xFFFFull);

  for (int j = tid; j < N; j += 256) su[j] = f64_ord(x[j]);
  __syncthreads();

  unsigned long long uth = 0xFFFFFFFFFFFFFFFFull;   // k==0: damp everything
  if (k > 0) {
    int t = N - k;                 // ascending 0-indexed rank of k-th largest
    unsigned long long prefix = 0;
    for (int shift = 56; shift >= 0; shift -= 8) {
      hist[tid] = 0;
      __syncthreads();
      unsigned long long pm =
          (shift == 56) ? 0ull : ~((1ull << (shift + 8)) - 1ull);
      for (int j = tid; j < N; j += 256) {
        unsigned long long u = su[j];
        if ((u & pm) == prefix) atomicAdd(&hist[(int)((u >> shift) & 255)], 1);
      }
      __syncthreads();
      int v = hist[tid];
      scan[tid] = v;
      __syncthreads();
      for (int d = 1; d < 256; d <<= 1) {
        int add = (tid >= d) ? scan[tid - d] : 0;
        __syncthreads();
        scan[tid] += add;
        __syncthreads();
      }
      int incl = scan[tid];
      int excl = incl - hist[tid];
      if (hist[tid] > 0 && t >= excl && t < incl) {
        s_bin = tid; s_base = excl; s_cnt = hist[tid];
      }
      __syncthreads();
      prefix |= ((unsigned long long)s_bin) << shift;
      t -= s_base;
      int cnt = s_cnt;
      __syncthreads();
      if (cnt == 1) break;   // unique element under this prefix: zero-filled
                             // low bits still classify every element correctly
    }
    uth = prefix;
  }
  __syncthreads();
  for (int j = tid; j < N; j += 256) {
    if (su[j] < uth) x[j] = x[j] / 3.0;
  }
}

// ---------------- launch ----------------
extern "C" void kernel_launch(void* const* d_in, const int* in_sizes, int n_in,
                              void* d_out, int out_size, void* d_ws, size_t ws_size,
                              hipStream_t stream)
{
  const float* state   = (const float*)d_in[0];
  const float* task    = (const float*)d_in[1];
  const float* action  = (const float*)d_in[2];
  const float* W_cx1_1 = (const float*)d_in[3];  const float* b_cx1_1 = (const float*)d_in[4];
  const float* W_cx1_2 = (const float*)d_in[5];  const float* b_cx1_2 = (const float*)d_in[6];
  const float* W_cx2_1 = (const float*)d_in[7];  const float* b_cx2_1 = (const float*)d_in[8];
  const float* W_cx2_2 = (const float*)d_in[9];  const float* b_cx2_2 = (const float*)d_in[10];
  const float* W_cx3_1 = (const float*)d_in[11]; const float* b_cx3_1 = (const float*)d_in[12];
  const float* W_cx3_2 = (const float*)d_in[13]; const float* b_cx3_2 = (const float*)d_in[14];
  const float* W_l1    = (const float*)d_in[15]; const float* b_l1    = (const float*)d_in[16];
  const float* W_l2    = (const float*)d_in[17]; const float* b_l2    = (const float*)d_in[18];
  const float* W_l3    = (const float*)d_in[19]; const float* b_l3    = (const float*)d_in[20];
  const float* W_l4    = (const float*)d_in[21]; const float* b_l4    = (const float*)d_in[22];

  // ---- workspace overlay (peak 218.37 MB, proven footprint) ----
  // region A [0, 134.22 MB):  tower h (fp32) -> a1 (fp64) -> a3 (fp64)
  // region B [134.22, 218.37): Cg (fp32)     -> a2 (fp64)
  // kpk (0.39 MB) lives at the front of d_out and is fully consumed before
  // the final GEMM overwrites d_out.
  char* wsb = (char*)d_ws;
  double* A1 = (double*)wsb;                       // 16384*1024*8 = 134,217,728
  float*  Hf = (float*)wsb;                        // towers' h, <= 67.1 MB
  double* A3 = (double*)wsb;                       // 16384*256*8 = 33.6 MB
  float*  Cg = (float*)(wsb + 134217728ULL);       // 16384*1284*4 = 84,148,224
  double* A2 = (double*)(wsb + 134217728ULL);      // 16384*512*8 = 67.1 MB
  unsigned long long* kpk = (unsigned long long*)d_out;

  dim3 blk(256);

  k_build_ctx<<<(NB * CSL) / 256, blk, 0, stream>>>(state, task, action, Cg);
  (void)hipMemsetAsync(kpk, 0, (size_t)3 * NB * 8, stream);

  // gate towers: h = tanh(ctx @ Wa^T + ba) (fp64 math, fp32 store);
  // then logits + fused row-argmax (softmax elided: argmax-invariant)
  g64m<4,0><<<dim3(NB/TM, 1024/TN), blk, 0, stream>>>(Cg, W_cx1_1, b_cx1_1, Hf, nullptr, 1024, KCTX);
  g64m<2,0><<<dim3(NB/TM, 1024/TN), blk, 0, stream>>>(Hf, W_cx1_2, b_cx1_2, nullptr, kpk,        1024, 1024);
  g64m<4,0><<<dim3(NB/TM,  512/TN), blk, 0, stream>>>(Cg, W_cx2_1, b_cx2_1, Hf, nullptr, 512, KCTX);
  g64m<2,0><<<dim3(NB/TM,  512/TN), blk, 0, stream>>>(Hf, W_cx2_2, b_cx2_2, nullptr, kpk + NB,    512,  512);
  g64m<4,0><<<dim3(NB/TM,  256/TN), blk, 0, stream>>>(Cg, W_cx3_1, b_cx3_1, Hf, nullptr, 256, KCTX);
  g64m<2,0><<<dim3(NB/TM,  256/TN), blk, 0, stream>>>(Hf, W_cx3_2, b_cx3_2, nullptr, kpk + 2*NB,  256,  256);

  // main chain, fp64 end to end
  g64m<0,0><<<dim3(NB/TM, 1024/TN), blk, 0, stream>>>(Cg, W_l1, b_l1, A1, nullptr, 1024, KCTX);
  k_kwta64<<<NB, blk, 0, stream>>>(A1, 1024, kpk);
  g64m<0,1><<<dim3(NB/TM,  512/TN), blk, 0, stream>>>(A1, W_l2, b_l2, A2, nullptr,  512, 1024);
  k_kwta64<<<NB, blk, 0, stream>>>(A2,  512, kpk + NB);
  g64m<0,1><<<dim3(NB/TM,  256/TN), blk, 0, stream>>>(A2, W_l3, b_l3, A3, nullptr,  256,  512);
  k_kwta64<<<NB, blk, 0, stream>>>(A3,  256, kpk + 2*NB);
  g64m<3,1><<<dim3(NB/TM,  256/TN), blk, 0, stream>>>(A3, W_l4, b_l4, d_out, nullptr, 256, 256);
}

// Round 7
// 2336.425 us; speedup vs baseline: 1.9898x; 1.4227x over previous
//
#include <hip/hip_runtime.h>
#include <math.h>

typedef float  v4f   __attribute__((ext_vector_type(4)));
typedef double v2d   __attribute__((ext_vector_type(2)));
typedef double v4d   __attribute__((ext_vector_type(4)));
typedef float  f32x4 __attribute__((ext_vector_type(4)));
typedef short  s16x8 __attribute__((ext_vector_type(8)));

#define NB   16384
#define KCTX 1284
#define CSL  (KCTX/4)    // 321 float4 per ctx row

// ---- fp64 MFMA: D[16x16] += A[16x4] * B[4x16], per-wave ----
#if defined(__has_builtin)
#  if __has_builtin(__builtin_amdgcn_mfma_f64_16x16x4f64)
#    define MFMA64(a, b, c) __builtin_amdgcn_mfma_f64_16x16x4f64((a), (b), (c), 0, 0, 0)
#  endif
#endif
#ifndef MFMA64
static __device__ __forceinline__ v4d mfma64_asm(double a, double b, v4d c) {
  asm volatile("v_mfma_f64_16x16x4_f64 %0, %1, %2, %0" : "+v"(c) : "v"(a), "v"(b));
  return c;
}
#  define MFMA64(a, b, c) mfma64_asm((a), (b), (c))
#endif

// ---- bf16 MFMA 16x16x32 via inline asm (ISA §10); gfx950 unified VGPR file ----
static __device__ __forceinline__ f32x4 mfma_bf16(s16x8 a, s16x8 b, f32x4 c) {
  asm("v_mfma_f32_16x16x32_bf16 %0, %1, %2, %0" : "+v"(c) : "v"(a), "v"(b));
  return c;
}

// ---------------- ctx concat [state | task | action], unpadded K=1284 -------
__global__ __launch_bounds__(256) void k_build_ctx(
    const float* __restrict__ state, const float* __restrict__ task,
    const float* __restrict__ action, float* __restrict__ Cg)
{
  int idx = blockIdx.x * 256 + threadIdx.x;      // float4 slot
  if (idx >= NB * CSL) return;
  int b = idx / CSL, s = idx - b * CSL;
  v4f v;
  if (s < 256)       v = *((const v4f*)state  + (size_t)b * 256 + s);
  else if (s == 256) v = *((const v4f*)task   + b);
  else               v = *((const v4f*)action + (size_t)b * 64 + (s - 257));
  *((v4f*)Cg + idx) = v;
}

__device__ __forceinline__ unsigned long long f64_ord(double f) {
  unsigned long long u = (unsigned long long)__double_as_longlong(f);
  return (u & 0x8000000000000000ull) ? ~u : (u | 0x8000000000000000ull);
}

// =================== fp64-MFMA GEMM (main chain) — UNCHANGED from r6 ========
// EPI: 0 = store f64, 2 = row-argmax only, 3 = store f32, 4 = tanh->f32
// ASRC: 0 = A fp32 (any K), 1 = A fp64 (K%16==0)
// D-layout (f64 16x16x4): col = lane&15, row = 4*reg + (lane>>4)
#define TM 128
#define TN 64
#define TK 16
#define LRA 130
#define LRB 66

template<int EPI, int ASRC>
__global__ __launch_bounds__(256, 3) void g64m(
    const void* __restrict__ Av, const float* __restrict__ W,
    const float* __restrict__ bias, void* __restrict__ Cv,
    unsigned long long* __restrict__ kpk, int N, int K)
{
  __shared__ __align__(16) double As[TK * LRA];
  __shared__ __align__(16) double Ws[TK * LRB];

  const int tid  = threadIdx.x;
  const int lane = tid & 63;
  const int wid  = tid >> 6;
  const int wm   = wid >> 1;
  const int wn   = wid & 1;
  const int grp  = lane >> 4;
  const int lid  = lane & 15;
  const int row0 = blockIdx.x * TM;
  const int col0 = blockIdx.y * TN;

  const int lrA = tid >> 1;
  const int lcA = (tid & 1) * 8;
  const int lrW = tid >> 2;
  const int lcW = (tid & 3) * 4;

  const float*  ApF = (const float*)Av  + (size_t)(row0 + lrA) * K;
  const double* ApD = (const double*)Av + (size_t)(row0 + lrA) * K;
  const float*  WpF = W + (size_t)(col0 + lrW) * K;

  double sa[8], sw[4];

  v4d acc[4][2];
  #pragma unroll
  for (int i = 0; i < 4; ++i)
    #pragma unroll
    for (int j = 0; j < 2; ++j) { acc[i][j][0] = 0.0; acc[i][j][1] = 0.0;
                                  acc[i][j][2] = 0.0; acc[i][j][3] = 0.0; }

  const int nt = (K + TK - 1) / TK;

  auto loadA = [&](int k0) {
    const int kb = k0 + lcA;
    if (ASRC == 0) {
      if (kb + 8 <= K) {
        v4f x0 = *(const v4f*)(ApF + kb), x1 = *(const v4f*)(ApF + kb + 4);
        sa[0] = x0.x; sa[1] = x0.y; sa[2] = x0.z; sa[3] = x0.w;
        sa[4] = x1.x; sa[5] = x1.y; sa[6] = x1.z; sa[7] = x1.w;
      } else {
        #pragma unroll
        for (int j = 0; j < 8; ++j) sa[j] = (kb + j < K) ? (double)ApF[kb + j] : 0.0;
      }
    } else {
      const double* p = ApD + kb;
      v2d d0 = *(const v2d*)p,       d1 = *(const v2d*)(p + 2);
      v2d d2 = *(const v2d*)(p + 4), d3 = *(const v2d*)(p + 6);
      sa[0] = d0.x; sa[1] = d0.y; sa[2] = d1.x; sa[3] = d1.y;
      sa[4] = d2.x; sa[5] = d2.y; sa[6] = d3.x; sa[7] = d3.y;
    }
  };
  auto loadW = [&](int k0) {
    const int kb = k0 + lcW;
    if (kb + 4 <= K) {
      v4f w0 = *(const v4f*)(WpF + kb);
      sw[0] = w0.x; sw[1] = w0.y; sw[2] = w0.z; sw[3] = w0.w;
    } else {
      #pragma unroll
      for (int j = 0; j < 4; ++j) sw[j] = (kb + j < K) ? (double)WpF[kb + j] : 0.0;
    }
  };

  loadA(0); loadW(0);

  for (int t = 0; t < nt; ++t) {
    __syncthreads();
    #pragma unroll
    for (int j = 0; j < 8; ++j) As[(lcA + j) * LRA + lrA] = sa[j];
    #pragma unroll
    for (int j = 0; j < 4; ++j) Ws[(lcW + j) * LRB + lrW] = sw[j];
    if (t + 1 < nt) { loadA((t + 1) * TK); loadW((t + 1) * TK); }
    __syncthreads();
    #pragma unroll
    for (int ks = 0; ks < 4; ++ks) {
      const double* Ar = As + (ks * 4 + grp) * LRA + wm * 64 + lid;
      const double* Br = Ws + (ks * 4 + grp) * LRB + wn * 32 + lid;
      double a[4], b[2];
      #pragma unroll
      for (int i = 0; i < 4; ++i) a[i] = Ar[i * 16];
      #pragma unroll
      for (int j = 0; j < 2; ++j) b[j] = Br[j * 16];
      #pragma unroll
      for (int i = 0; i < 4; ++i)
        #pragma unroll
        for (int j = 0; j < 2; ++j)
          acc[i][j] = MFMA64(a[i], b[j], acc[i][j]);
    }
  }

  double bb[2];
  #pragma unroll
  for (int j = 0; j < 2; ++j) bb[j] = (double)bias[col0 + wn * 32 + j * 16 + lid];

  if (EPI == 0) {
    #pragma unroll
    for (int i = 0; i < 4; ++i)
      #pragma unroll
      for (int r = 0; r < 4; ++r) {
        int row = row0 + wm * 64 + i * 16 + r * 4 + grp;
        double* Cp = (double*)Cv + (size_t)row * N + col0 + wn * 32 + lid;
        #pragma unroll
        for (int j = 0; j < 2; ++j) Cp[j * 16] = acc[i][j][r] + bb[j];
      }
  } else if (EPI == 3 || EPI == 4) {
    #pragma unroll
    for (int i = 0; i < 4; ++i)
      #pragma unroll
      for (int r = 0; r < 4; ++r) {
        int row = row0 + wm * 64 + i * 16 + r * 4 + grp;
        float* Cp = (float*)Cv + (size_t)row * N + col0 + wn * 32 + lid;
        #pragma unroll
        for (int j = 0; j < 2; ++j) {
          double o = acc[i][j][r] + bb[j];
          if (EPI == 4) o = tanh(o);
          Cp[j * 16] = (float)o;
        }
      }
  } else {
    #pragma unroll
    for (int i = 0; i < 4; ++i)
      #pragma unroll
      for (int r = 0; r < 4; ++r) {
        int row = row0 + wm * 64 + i * 16 + r * 4 + grp;
        double best = acc[i][0][r] + bb[0];
        int bcol = col0 + wn * 32 + lid;
        {
          double v = acc[i][1][r] + bb[1];
          if (v > best) { best = v; bcol = col0 + wn * 32 + 16 + lid; }
        }
        #pragma unroll
        for (int d = 1; d < 16; d <<= 1) {
          double ov = __shfl_xor(best, d);
          int    oc = __shfl_xor(bcol, d);
          if (ov > best || (ov == best && oc < bcol)) { best = ov; bcol = oc; }
        }
        if (lid == 0) {
          unsigned long long key =
              (f64_ord(best) & ~0xFFFFull) | ((~(unsigned)bcol) & 0xFFFFu);
          atomicMax(&kpk[row], key);
        }
      }
  }
}

// =================== bf16x3 tower GEMM ======================================
// C = A[M,K](f32) * W[N,K]^T(f32) + bias, computed as 3-way exact truncation
// split a=a1+a2+a3 (8 mantissa bits each, exact), 6 bf16-MFMA products in 3
// magnitude groups; hi group flushed to fp64 shadow every 8 tiles (K=256).
// EPI: 4 = tanh -> f32 store; 2 = row-argmax only (packed atomicMax).
// D-layout (bf16 16x16x32, m89-verified): col=lane&15, row=(lane>>4)*4+reg
#define GTM 128
#define GTN 64
#define GTK 32
#define GLR 40    // ushort per LDS row: 32 + 8 pad (16B-aligned rows, 2-way banks)

template<int EPI>
__global__ __launch_bounds__(256, 2) void g16(
    const float* __restrict__ A, const float* __restrict__ W,
    const float* __restrict__ bias, float* __restrict__ C,
    unsigned long long* __restrict__ kpk, int N, int K)
{
  __shared__ __align__(16) unsigned short Al[3][GTM * GLR];
  __shared__ __align__(16) unsigned short Wl[3][GTN * GLR];

  const int tid  = threadIdx.x;
  const int lane = tid & 63;
  const int wid  = tid >> 6;
  const int wm   = wid >> 1;        // 64-row half
  const int wn   = wid & 1;         // 32-col half
  const int grp  = lane >> 4;
  const int lid  = lane & 15;
  const int row0 = blockIdx.x * GTM;
  const int col0 = blockIdx.y * GTN;

  const int arow = tid >> 1, akc = (tid & 1) * 16;   // A loader: 16 k each
  const int wrow = tid >> 2, wkc = (tid & 3) * 8;    // W loader: 8 k each
  const float* Ap = A + (size_t)(row0 + arow) * K;
  const float* Wp = W + (size_t)(col0 + wrow) * K;

  float av[16], wv[8];

  f32x4 ah[4][2], am[4][2], al[4][2];
  double sh[4][2][4];
  #pragma unroll
  for (int i = 0; i < 4; ++i)
    #pragma unroll
    for (int j = 0; j < 2; ++j) {
      ah[i][j] = (f32x4)0.f; am[i][j] = (f32x4)0.f; al[i][j] = (f32x4)0.f;
      #pragma unroll
      for (int r = 0; r < 4; ++r) sh[i][j][r] = 0.0;
    }

  const int nt = (K + GTK - 1) / GTK;

  auto loadA = [&](int kb) {
    #pragma unroll
    for (int q = 0; q < 4; ++q) {
      int k = kb + akc + q * 4;
      if (k + 4 <= K) {
        v4f x = *(const v4f*)(Ap + k);
        av[q*4+0] = x.x; av[q*4+1] = x.y; av[q*4+2] = x.z; av[q*4+3] = x.w;
      } else {
        #pragma unroll
        for (int j = 0; j < 4; ++j) av[q*4+j] = (k + j < K) ? Ap[k + j] : 0.f;
      }
    }
  };
  auto loadW = [&](int kb) {
    #pragma unroll
    for (int q = 0; q < 2; ++q) {
      int k = kb + wkc + q * 4;
      if (k + 4 <= K) {
        v4f x = *(const v4f*)(Wp + k);
        wv[q*4+0] = x.x; wv[q*4+1] = x.y; wv[q*4+2] = x.z; wv[q*4+3] = x.w;
      } else {
        #pragma unroll
        for (int j = 0; j < 4; ++j) wv[q*4+j] = (k + j < K) ? Wp[k + j] : 0.f;
      }
    }
  };

  // exact truncation split: v = s1 + s2 + s3 (bf16 bit patterns), no rounding
  auto split8 = [](const float* v, s16x8& p1, s16x8& p2, s16x8& p3) {
    #pragma unroll
    for (int j = 0; j < 8; ++j) {
      unsigned u1 = __float_as_uint(v[j]);
      float f1 = __uint_as_float(u1 & 0xFFFF0000u);
      float r1 = v[j] - f1;
      unsigned u2 = __float_as_uint(r1);
      float f2 = __uint_as_float(u2 & 0xFFFF0000u);
      float r2 = r1 - f2;
      unsigned u3 = __float_as_uint(r2);
      p1[j] = (short)(u1 >> 16); p2[j] = (short)(u2 >> 16); p3[j] = (short)(u3 >> 16);
    }
  };

  loadA(0); loadW(0);

  for (int t = 0; t < nt; ++t) {
    __syncthreads();
    #pragma unroll
    for (int h = 0; h < 2; ++h) {
      s16x8 p1, p2, p3;
      split8(&av[h * 8], p1, p2, p3);
      *(s16x8*)&Al[0][arow * GLR + akc + h * 8] = p1;
      *(s16x8*)&Al[1][arow * GLR + akc + h * 8] = p2;
      *(s16x8*)&Al[2][arow * GLR + akc + h * 8] = p3;
    }
    {
      s16x8 q1, q2, q3;
      split8(&wv[0], q1, q2, q3);
      *(s16x8*)&Wl[0][wrow * GLR + wkc] = q1;
      *(s16x8*)&Wl[1][wrow * GLR + wkc] = q2;
      *(s16x8*)&Wl[2][wrow * GLR + wkc] = q3;
    }
    if (t + 1 < nt) { loadA((t + 1) * GTK); loadW((t + 1) * GTK); }
    __syncthreads();

    s16x8 b0[2], b1[2], b2[2];
    #pragma unroll
    for (int nf = 0; nf < 2; ++nf) {
      int widx = (wn * 32 + nf * 16 + lid) * GLR + grp * 8;
      b0[nf] = *(const s16x8*)&Wl[0][widx];
      b1[nf] = *(const s16x8*)&Wl[1][widx];
      b2[nf] = *(const s16x8*)&Wl[2][widx];
    }
    #pragma unroll
    for (int mf = 0; mf < 4; ++mf) {
      int aidx = (wm * 64 + mf * 16 + lid) * GLR + grp * 8;
      s16x8 a0 = *(const s16x8*)&Al[0][aidx];
      s16x8 a1 = *(const s16x8*)&Al[1][aidx];
      s16x8 a2 = *(const s16x8*)&Al[2][aidx];
      #pragma unroll
      for (int nf = 0; nf < 2; ++nf) {
        ah[mf][nf] = mfma_bf16(a0, b0[nf], ah[mf][nf]);
        am[mf][nf] = mfma_bf16(a0, b1[nf], am[mf][nf]);
        am[mf][nf] = mfma_bf16(a1, b0[nf], am[mf][nf]);
        al[mf][nf] = mfma_bf16(a0, b2[nf], al[mf][nf]);
        al[mf][nf] = mfma_bf16(a1, b1[nf], al[mf][nf]);
        al[mf][nf] = mfma_bf16(a2, b0[nf], al[mf][nf]);
      }
    }
    if ((t & 7) == 7) {     // flush hi group to fp64 shadow (K=256 chunks)
      asm volatile("s_nop 7\n\ts_nop 7");   // MFMA->VALU read guard (inline asm)
      #pragma unroll
      for (int mf = 0; mf < 4; ++mf)
        #pragma unroll
        for (int nf = 0; nf < 2; ++nf) {
          #pragma unroll
          for (int r = 0; r < 4; ++r) sh[mf][nf][r] += (double)ah[mf][nf][r];
          ah[mf][nf] = (f32x4)0.f;
        }
    }
  }

  asm volatile("s_nop 7\n\ts_nop 7");
  #pragma unroll
  for (int mf = 0; mf < 4; ++mf)
    #pragma unroll
    for (int nf = 0; nf < 2; ++nf)
      #pragma unroll
      for (int r = 0; r < 4; ++r) sh[mf][nf][r] += (double)ah[mf][nf][r];

  double bb[2];
  #pragma unroll
  for (int nf = 0; nf < 2; ++nf) bb[nf] = (double)bias[col0 + wn * 32 + nf * 16 + lid];

  if (EPI == 4) {
    #pragma unroll
    for (int mf = 0; mf < 4; ++mf)
      #pragma unroll
      for (int r = 0; r < 4; ++r) {
        int row = row0 + wm * 64 + mf * 16 + grp * 4 + r;
        float* Cp = C + (size_t)row * N + col0 + wn * 32 + lid;
        #pragma unroll
        for (int nf = 0; nf < 2; ++nf) {
          double o = sh[mf][nf][r] + (double)am[mf][nf][r] + (double)al[mf][nf][r] + bb[nf];
          Cp[nf * 16] = (float)tanh(o);
        }
      }
  } else {
    #pragma unroll
    for (int mf = 0; mf < 4; ++mf)
      #pragma unroll
      for (int r = 0; r < 4; ++r) {
        int row = row0 + wm * 64 + mf * 16 + grp * 4 + r;
        double v0 = sh[mf][0][r] + (double)am[mf][0][r] + (double)al[mf][0][r] + bb[0];
        double v1 = sh[mf][1][r] + (double)am[mf][1][r] + (double)al[mf][1][r] + bb[1];
        double best = v0; int bcol = col0 + wn * 32 + lid;
        if (v1 > best) { best = v1; bcol = col0 + wn * 32 + 16 + lid; }
        #pragma unroll
        for (int d = 1; d < 16; d <<= 1) {
          double ov = __shfl_xor(best, d);
          int    oc = __shfl_xor(bcol, d);
          if (ov > best || (ov == best && oc < bcol)) { best = ov; bcol = oc; }
        }
        if (lid == 0) {
          unsigned long long key =
              (f64_ord(best) & ~0xFFFFull) | ((~(unsigned)bcol) & 0xFFFFu);
          atomicMax(&kpk[row], key);
        }
      }
  }
}

// ---------------- kwta on fp64: exact radix-select of k-th largest ----------
__global__ __launch_bounds__(256) void k_kwta64(
    double* __restrict__ X, int N, const unsigned long long* __restrict__ kpk)
{
  const int row = blockIdx.x;
  const int tid = threadIdx.x;
  double* x = X + (size_t)row * N;
  __shared__ unsigned long long su[1024];
  __shared__ int hist[256];
  __shared__ int scan[256];
  __shared__ int s_bin, s_base, s_cnt;

  unsigned long long p = kpk[row];
  int k = (int)((~p) & 0xFFFFull);

  for (int j = tid; j < N; j += 256) su[j] = f64_ord(x[j]);
  __syncthreads();

  unsigned long long uth = 0xFFFFFFFFFFFFFFFFull;
  if (k > 0) {
    int t = N - k;
    unsigned long long prefix = 0;
    for (int shift = 56; shift >= 0; shift -= 8) {
      hist[tid] = 0;
      __syncthreads();
      unsigned long long pm =
          (shift == 56) ? 0ull : ~((1ull << (shift + 8)) - 1ull);
      for (int j = tid; j < N; j += 256) {
        unsigned long long u = su[j];
        if ((u & pm) == prefix) atomicAdd(&hist[(int)((u >> shift) & 255)], 1);
      }
      __syncthreads();
      int v = hist[tid];
      scan[tid] = v;
      __syncthreads();
      for (int d = 1; d < 256; d <<= 1) {
        int add = (tid >= d) ? scan[tid - d] : 0;
        __syncthreads();
        scan[tid] += add;
        __syncthreads();
      }
      int incl = scan[tid];
      int excl = incl - hist[tid];
      if (hist[tid] > 0 && t >= excl && t < incl) {
        s_bin = tid; s_base = excl; s_cnt = hist[tid];
      }
      __syncthreads();
      prefix |= ((unsigned long long)s_bin) << shift;
      t -= s_base;
      int cnt = s_cnt;
      __syncthreads();
      if (cnt == 1) break;
    }
    uth = prefix;
  }
  __syncthreads();
  for (int j = tid; j < N; j += 256) {
    if (su[j] < uth) x[j] = x[j] / 3.0;
  }
}

// ---------------- launch ----------------
extern "C" void kernel_launch(void* const* d_in, const int* in_sizes, int n_in,
                              void* d_out, int out_size, void* d_ws, size_t ws_size,
                              hipStream_t stream)
{
  const float* state   = (const float*)d_in[0];
  const float* task    = (const float*)d_in[1];
  const float* action  = (const float*)d_in[2];
  const float* W_cx1_1 = (const float*)d_in[3];  const float* b_cx1_1 = (const float*)d_in[4];
  const float* W_cx1_2 = (const float*)d_in[5];  const float* b_cx1_2 = (const float*)d_in[6];
  const float* W_cx2_1 = (const float*)d_in[7];  const float* b_cx2_1 = (const float*)d_in[8];
  const float* W_cx2_2 = (const float*)d_in[9];  const float* b_cx2_2 = (const float*)d_in[10];
  const float* W_cx3_1 = (const float*)d_in[11]; const float* b_cx3_1 = (const float*)d_in[12];
  const float* W_cx3_2 = (const float*)d_in[13]; const float* b_cx3_2 = (const float*)d_in[14];
  const float* W_l1    = (const float*)d_in[15]; const float* b_l1    = (const float*)d_in[16];
  const float* W_l2    = (const float*)d_in[17]; const float* b_l2    = (const float*)d_in[18];
  const float* W_l3    = (const float*)d_in[19]; const float* b_l3    = (const float*)d_in[20];
  const float* W_l4    = (const float*)d_in[21]; const float* b_l4    = (const float*)d_in[22];

  // ---- workspace overlay (peak 218.37 MB, proven footprint) ----
  char* wsb = (char*)d_ws;
  double* A1 = (double*)wsb;                       // 134.2 MB
  float*  Hf = (float*)wsb;                        // towers' h, <= 67.1 MB
  double* A3 = (double*)wsb;                       // 33.6 MB
  float*  Cg = (float*)(wsb + 134217728ULL);       // 84.1 MB
  double* A2 = (double*)(wsb + 134217728ULL);      // 67.1 MB
  unsigned long long* kpk = (unsigned long long*)d_out;

  dim3 blk(256);

  k_build_ctx<<<(NB * CSL) / 256, blk, 0, stream>>>(state, task, action, Cg);
  (void)hipMemsetAsync(kpk, 0, (size_t)3 * NB * 8, stream);

  // gate towers (bf16x3 MFMA, fp32-class precision — argmax-safe per r1 evidence)
  g16<4><<<dim3(NB/GTM, 1024/GTN), blk, 0, stream>>>(Cg, W_cx1_1, b_cx1_1, Hf, nullptr, 1024, KCTX);
  g16<2><<<dim3(NB/GTM, 1024/GTN), blk, 0, stream>>>(Hf, W_cx1_2, b_cx1_2, nullptr, kpk,        1024, 1024);
  g16<4><<<dim3(NB/GTM,  512/GTN), blk, 0, stream>>>(Cg, W_cx2_1, b_cx2_1, Hf, nullptr, 512, KCTX);
  g16<2><<<dim3(NB/GTM,  512/GTN), blk, 0, stream>>>(Hf, W_cx2_2, b_cx2_2, nullptr, kpk + NB,    512,  512);
  g16<4><<<dim3(NB/GTM,  256/GTN), blk, 0, stream>>>(Cg, W_cx3_1, b_cx3_1, Hf, nullptr, 256, KCTX);
  g16<2><<<dim3(NB/GTM,  256/GTN), blk, 0, stream>>>(Hf, W_cx3_2, b_cx3_2, nullptr, kpk + 2*NB,  256,  256);

  // main chain, fp64 end to end (decision-exact)
  g64m<0,0><<<dim3(NB/TM, 1024/TN), blk, 0, stream>>>(Cg, W_l1, b_l1, A1, nullptr, 1024, KCTX);
  k_kwta64<<<NB, blk, 0, stream>>>(A1, 1024, kpk);
  g64m<0,1><<<dim3(NB/TM,  512/TN), blk, 0, stream>>>(A1, W_l2, b_l2, A2, nullptr,  512, 1024);
  k_kwta64<<<NB, blk, 0, stream>>>(A2,  512, kpk + NB);
  g64m<0,1><<<dim3(NB/TM,  256/TN), blk, 0, stream>>>(A2, W_l3, b_l3, A3, nullptr,  256,  512);
  k_kwta64<<<NB, blk, 0, stream>>>(A3,  256, kpk + 2*NB);
  g64m<3,1><<<dim3(NB/TM,  256/TN), blk, 0, stream>>>(A3, W_l4, b_l4, d_out, nullptr, 256, 256);
}